// Round 6
// baseline (753.382 us; speedup 1.0000x reference)
//
#include <hip/hip_runtime.h>
#include <stdint.h>

// Problem constants: N=262144 rows, C=256 channels, K=256 codes.
#define CCH 256
#define KK  256

typedef int   i32x4 __attribute__((ext_vector_type(4)));
typedef float f32x4 __attribute__((ext_vector_type(4)));
typedef unsigned short u16x8 __attribute__((ext_vector_type(8)));

// Async global->LDS DMA, 16 B per lane.  Global address is per-lane; LDS
// destination is wave-uniform base + lane*16 (m97/m104 semantics).
typedef const __attribute__((address_space(1))) void gas_t;
typedef __attribute__((address_space(3))) void las_t;
__device__ __forceinline__ void gl_lds16(const void* g, void* l) {
  __builtin_amdgcn_global_load_lds((gas_t*)g, (las_t*)l, 16, 0, 0);
}

// ---------------------------------------------------------------------------
// K0: compress white_table int32 -> uint8.
// ---------------------------------------------------------------------------
__global__ __launch_bounds__(256) void compress_table_kernel(
    const int4* __restrict__ t, uchar4* __restrict__ o, int n4) {
  int i = blockIdx.x * 256 + threadIdx.x;
  if (i < n4) {
    int4 v = t[i];
    o[i] = make_uchar4((unsigned char)v.x, (unsigned char)v.y,
                       (unsigned char)v.z, (unsigned char)v.w);
  }
}

// ---------------------------------------------------------------------------
// K1 v6: transpose+pack with ASYNC global->LDS pipeline (T3/T4 pattern).
// L,R [N,C] i32 -> LRtT tile-major [nslice/32][C][32] u16 = (l<<8)|r.
// Per block: 16 subtiles of 16 rows.  Raw L,R rows DMA'd into LDS
// (double-buffered, 2 x 32 KB); counted vmcnt(5) keeps the next subtile's
// loads in flight across the whole pack+store phase -- never drains to 0.
// Phase B: thread (c = tid>>1, hh = tid&1) packs 8 rows of channel c and
// stores 16 B.  LDS reads: pairs of lanes share an address (broadcast) ->
// 2-way, free.  Waves 0-3 DMA L, waves 4-7 DMA R (wave-uniform branch).
// ---------------------------------------------------------------------------
__global__ __launch_bounds__(512, 1) void transpose_pack_kernel(
    const unsigned char* __restrict__ Lg, const unsigned char* __restrict__ Rg,
    unsigned short* __restrict__ LRtT, int n0_base, int nslice) {
  __shared__ unsigned int lds[2][8192];  // [buf][ L rows 0..4095 | R rows 4096.. ]
  const int tid  = threadIdx.x;
  const int w    = tid >> 6;
  const int lane = tid & 63;
  const int g0   = blockIdx.x * 16;      // first slice-local 16-row subtile
  const bool isR = (w >= 4);
  const int  wi  = w & 3;
  const unsigned char* src = isR ? Rg : Lg;
  const int ldsoff = (isR ? 4096 : 0) + wi * 4 * 256;

  const int c  = tid >> 1;  // channel 0..255
  const int hh = tid & 1;   // row octet

#define ISSUE(t, b)                                                            \
  {                                                                            \
    const unsigned char* p = src +                                             \
        ((size_t)(n0_base + (g0 + (t)) * 16) + (size_t)(wi * 4)) * 1024 +      \
        lane * 16;                                                             \
    unsigned int* d = &lds[b][ldsoff];                                         \
    gl_lds16(p,        d);                                                     \
    gl_lds16(p + 1024, d + 256);                                               \
    gl_lds16(p + 2048, d + 512);                                               \
    gl_lds16(p + 3072, d + 768);                                               \
  }

#define PHASE_B(t, b)                                                          \
  {                                                                            \
    const unsigned int* Lr = &lds[b][0];                                       \
    const unsigned int* Rr = &lds[b][4096];                                    \
    u16x8 v;                                                                   \
    _Pragma("unroll")                                                          \
    for (int r = 0; r < 8; ++r) {                                              \
      unsigned lv = Lr[(hh * 8 + r) * 256 + c];                                \
      unsigned rv = Rr[(hh * 8 + r) * 256 + c];                                \
      v[r] = (unsigned short)((lv << 8) | rv);                                 \
    }                                                                          \
    const int gt = g0 + (t);                                                   \
    *(u16x8*)&LRtT[((size_t)(gt >> 1) * 256 + c) * 32 + (gt & 1) * 16 +        \
                   hh * 8] = v;                                                \
  }

  ISSUE(0, 0);
#pragma unroll 1
  for (int t = 0; t < 15; ++t) {
    ISSUE(t + 1, (t + 1) & 1);
    // Wait only for tile t's 4 loads: outstanding afterwards = next tile's
    // 4 loads (+ last store).  t=0 has no store in the queue yet.
    if (t == 0) asm volatile("s_waitcnt vmcnt(4)" ::: "memory");
    else        asm volatile("s_waitcnt vmcnt(5)" ::: "memory");
    __builtin_amdgcn_s_barrier();
    PHASE_B(t, t & 1);
    __builtin_amdgcn_s_barrier();
  }
  asm volatile("s_waitcnt vmcnt(1)" ::: "memory");
  __builtin_amdgcn_s_barrier();
  PHASE_B(15, 1);
#undef ISSUE
#undef PHASE_B
}

// ---------------------------------------------------------------------------
// K2: per-channel code gather, 64 KB table in LDS, 512 threads, 2 blocks/CU.
// Inputs (128 B/thread) loaded to VGPR first; table then DMA'd via
// global_load_lds (no VGPR roundtrip) -- both overlap until __syncthreads.
// blockIdx&255 = channel -> all of a channel's blocks on one XCD.
// ---------------------------------------------------------------------------
__global__ __launch_bounds__(512, 4) void code_gather_kernel(
    const unsigned short* __restrict__ LRtT, const unsigned char* __restrict__ tab8,
    unsigned char* __restrict__ codes, int nslice) {
  __shared__ unsigned char tabs[KK * KK];  // 64 KB
  const int c   = blockIdx.x & (CCH - 1);
  const int sub = blockIdx.x >> 8;
  const int tid = threadIdx.x;
  const int tbase = sub * 1024;            // first 32-row tile of this block

  u16x8 v[8];
#pragma unroll
  for (int i = 0; i < 8; ++i) {
    const size_t a =
        ((size_t)(tbase + i * 128 + (tid >> 2)) * CCH + c) * 32 + (tid & 3) * 8;
    v[i] = *(const u16x8*)(LRtT + a);
  }
  {
    const int w = tid >> 6, lane = tid & 63;
    const unsigned char* tsrc = tab8 + (size_t)c * (KK * KK) + w * 8192 + lane * 16;
    unsigned int* tdst = (unsigned int*)tabs + w * 2048;
#pragma unroll
    for (int i = 0; i < 8; ++i) gl_lds16(tsrc + i * 1024, tdst + i * 256);
  }
  __syncthreads();  // drains vmcnt(0): table in LDS, inputs in VGPRs

  uint2* outp = (uint2*)(codes + (size_t)c * nslice + (size_t)sub * 32768);
#pragma unroll
  for (int i = 0; i < 8; ++i) {
    unsigned lo = (unsigned)tabs[v[i][0]] | ((unsigned)tabs[v[i][1]] << 8) |
                  ((unsigned)tabs[v[i][2]] << 16) | ((unsigned)tabs[v[i][3]] << 24);
    unsigned hi = (unsigned)tabs[v[i][4]] | ((unsigned)tabs[v[i][5]] << 8) |
                  ((unsigned)tabs[v[i][6]] << 16) | ((unsigned)tabs[v[i][7]] << 24);
    outp[i * 512 + tid] = make_uint2(lo, hi);
  }
}

// ---------------------------------------------------------------------------
// K3: codebook + transpose back (unchanged from round 5).
// ---------------------------------------------------------------------------
__global__ __launch_bounds__(512, 6) void codebook_transpose_kernel(
    const unsigned char* __restrict__ codes, const float* __restrict__ cb,
    float* __restrict__ out, int n0_base, int nslice) {
  __shared__ float    cbs[32 * KK];   // 32 KB
  __shared__ unsigned ctd[32 * 65];   // 8.5 KB, pitch 65 dwords
  const int cg = blockIdx.x & 7;
  const int tn = blockIdx.x >> 3;
  const int c0 = cg * 32;
  const int tid = threadIdx.x;

  {
    const f32x4* cbg = (const f32x4*)(cb + (size_t)c0 * KK);
    f32x4* cbl = (f32x4*)cbs;
#pragma unroll
    for (int i = 0; i < 4; ++i) cbl[i * 512 + tid] = cbg[i * 512 + tid];
  }
  {
    const int cc = tid >> 4;  // 0..31
    const int s  = tid & 15;  // 0..15
    const uint4 val = *(const uint4*)(codes + (size_t)(c0 + cc) * nslice +
                                      (size_t)tn * 256 + s * 16);
    const int d0 = cc * 65 + s * 4;
    ctd[d0 + 0] = val.x;
    ctd[d0 + 1] = val.y;
    ctd[d0 + 2] = val.z;
    ctd[d0 + 3] = val.w;
  }
  __syncthreads();

  const int cq = tid & 7;   // channel quad 0..7
  const int nb = tid >> 3;  // 0..63 (4-row group)
  const unsigned cw0 = ctd[(cq * 4 + 0) * 65 + nb];
  const unsigned cw1 = ctd[(cq * 4 + 1) * 65 + nb];
  const unsigned cw2 = ctd[(cq * 4 + 2) * 65 + nb];
  const unsigned cw3 = ctd[(cq * 4 + 3) * 65 + nb];
  const float* b0 = cbs + (cq * 4 + 0) * KK;
  const float* b1 = cbs + (cq * 4 + 1) * KK;
  const float* b2 = cbs + (cq * 4 + 2) * KK;
  const float* b3 = cbs + (cq * 4 + 3) * KK;
  float* ob = out + (size_t)(n0_base + tn * 256 + nb * 4) * CCH + c0 + cq * 4;
#pragma unroll
  for (int k = 0; k < 4; ++k) {
    f32x4 o;
    o[0] = b0[(cw0 >> (8 * k)) & 255u];
    o[1] = b1[(cw1 >> (8 * k)) & 255u];
    o[2] = b2[(cw2 >> (8 * k)) & 255u];
    o[3] = b3[(cw3 >> (8 * k)) & 255u];
    __builtin_nontemporal_store(o, (f32x4*)(ob + (size_t)k * CCH));
  }
}

// ---------------------------------------------------------------------------
// Fallback: TA-path gather, used only if workspace is tiny.
// ---------------------------------------------------------------------------
#define ROWS_PER_BLOCK 512
#define NGROUPS 16
#define GCH (CCH / NGROUPS)

template <typename TabT>
__global__ __launch_bounds__(256, 8) void gather_kernel(
    const i32x4* __restrict__ left, const i32x4* __restrict__ right,
    const TabT* __restrict__ tab, const float* __restrict__ cb,
    f32x4* __restrict__ out, int nrows) {
  __shared__ float cbs[GCH * KK];
  const int g     = blockIdx.x & (NGROUPS - 1);
  const int chunk = blockIdx.x / NGROUPS;
  const int q     = threadIdx.x & 3;
  const int rsub  = threadIdx.x >> 2;
  {
    const f32x4* cbg = (const f32x4*)(cb + (size_t)(g * GCH) * KK);
    f32x4* cbl = (f32x4*)cbs;
#pragma unroll
    for (int i = 0; i < 4; ++i) cbl[threadIdx.x + i * 256] = cbg[threadIdx.x + i * 256];
  }
  __syncthreads();
  const int cbase  = g * GCH + q * 4;
  const TabT* t0   = tab + (size_t)cbase * (KK * KK);
  const int vecoff = g * 4 + q;
  const float* cq  = cbs + (q * 4) * KK;
  const int rbase = chunk * ROWS_PER_BLOCK;
#pragma unroll
  for (int it = 0; it < ROWS_PER_BLOCK / 32; ++it) {
    const int r0 = rbase + it * 32 + rsub;
    if (r0 >= nrows) break;
    const unsigned v0 = (unsigned)r0 * 64u + (unsigned)vecoff;
    i32x4 L0 = left[v0];
    i32x4 R0 = right[v0];
    unsigned c0 = (unsigned)t0[          (unsigned)(L0[0] * KK + R0[0])];
    unsigned c1 = (unsigned)t0[ 65536u + (unsigned)(L0[1] * KK + R0[1])];
    unsigned c2 = (unsigned)t0[131072u + (unsigned)(L0[2] * KK + R0[2])];
    unsigned c3 = (unsigned)t0[196608u + (unsigned)(L0[3] * KK + R0[3])];
    f32x4 o;
    o[0] = cq[       c0];
    o[1] = cq[KK   + c1];
    o[2] = cq[2*KK + c2];
    o[3] = cq[3*KK + c3];
    out[v0] = o;
  }
}

extern "C" void kernel_launch(void* const* d_in, const int* in_sizes, int n_in,
                              void* d_out, int out_size, void* d_ws, size_t ws_size,
                              hipStream_t stream) {
  const int*   left  = (const int*)d_in[0];
  const int*   right = (const int*)d_in[1];
  const int*   wt    = (const int*)d_in[2];   // [C, K, K] int32
  const float* cb    = (const float*)d_in[3]; // [C, K] float32
  float* out = (float*)d_out;

  const int nrows = in_sizes[0] / CCH;        // 262144
  const int tab_elems = CCH * KK * KK;        // 16,777,216
  const size_t tab_bytes = (size_t)tab_elems; // u8 table = 16 MB

  // Pick smallest slicing S whose workspace fits:
  //   need = 16 MB table + 512*nslice (LRtT u16) + 256*nslice (codes u8)
  // Kernel divisibility requires nslice % 32768 == 0.
  int S = 0;
  for (int s = 1; s <= 8; s <<= 1) {
    if (nrows % (s * 32768)) continue;
    size_t need = tab_bytes + (size_t)768 * (size_t)(nrows / s);
    if (need <= ws_size) { S = s; break; }
  }

  if (S) {
    unsigned char* tab8 = (unsigned char*)d_ws;
    int n4 = tab_elems / 4;
    compress_table_kernel<<<n4 / 256, 256, 0, stream>>>(
        (const int4*)wt, (uchar4*)tab8, n4);

    const int nslice = nrows / S;
    unsigned short* LRtT = (unsigned short*)((char*)d_ws + tab_bytes);
    unsigned char* codes = (unsigned char*)d_ws + tab_bytes + (size_t)512 * nslice;

    for (int h = 0; h < S; ++h) {
      const int n0 = h * nslice;
      transpose_pack_kernel<<<nslice / 256, 512, 0, stream>>>(
          (const unsigned char*)left, (const unsigned char*)right, LRtT, n0,
          nslice);
      code_gather_kernel<<<(nslice / 32768) * CCH, 512, 0, stream>>>(
          LRtT, tab8, codes, nslice);
      codebook_transpose_kernel<<<(nslice / 256) * 8, 512, 0, stream>>>(
          codes, cb, out, n0, nslice);
    }
  } else if (ws_size >= tab_bytes) {
    unsigned char* tab8 = (unsigned char*)d_ws;
    int n4 = tab_elems / 4;
    compress_table_kernel<<<n4 / 256, 256, 0, stream>>>(
        (const int4*)wt, (uchar4*)tab8, n4);
    const int blocks = ((nrows + ROWS_PER_BLOCK - 1) / ROWS_PER_BLOCK) * NGROUPS;
    gather_kernel<unsigned char><<<blocks, 256, 0, stream>>>(
        (const i32x4*)left, (const i32x4*)right, tab8, cb, (f32x4*)out, nrows);
  } else {
    const int blocks = ((nrows + ROWS_PER_BLOCK - 1) / ROWS_PER_BLOCK) * NGROUPS;
    gather_kernel<int><<<blocks, 256, 0, stream>>>(
        (const i32x4*)left, (const i32x4*)right, wt, cb, (f32x4*)out, nrows);
  }
}

// Round 7
// 704.628 us; speedup vs baseline: 1.0692x; 1.0692x over previous
//
#include <hip/hip_runtime.h>
#include <stdint.h>

// Problem constants: N=262144 rows, C=256 channels, K=256 codes.
#define CCH 256
#define KK  256

typedef int   i32x4 __attribute__((ext_vector_type(4)));
typedef float f32x4 __attribute__((ext_vector_type(4)));
typedef unsigned short u16x4 __attribute__((ext_vector_type(4)));
typedef unsigned short u16x8 __attribute__((ext_vector_type(8)));

// Async global->LDS DMA, 16 B per lane (wave-uniform LDS base + lane*16).
typedef const __attribute__((address_space(1))) void gas_t;
typedef __attribute__((address_space(3))) void las_t;
__device__ __forceinline__ void gl_lds16(const void* g, void* l) {
  __builtin_amdgcn_global_load_lds((gas_t*)g, (las_t*)l, 16, 0, 0);
}

// ---------------------------------------------------------------------------
// K0: compress white_table int32 -> uint8.
// ---------------------------------------------------------------------------
__global__ __launch_bounds__(256) void compress_table_kernel(
    const int4* __restrict__ t, uchar4* __restrict__ o, int n4) {
  int i = blockIdx.x * 256 + threadIdx.x;
  if (i < n4) {
    int4 v = t[i];
    o[i] = make_uchar4((unsigned char)v.x, (unsigned char)v.y,
                       (unsigned char)v.z, (unsigned char)v.w);
  }
}

// ---------------------------------------------------------------------------
// K1: transpose + pack (round-4 structure -- best measured: 163.5 us at S=1).
// L,R [N,C] i32 -> LRt [C, nslice] u16 = (l<<8)|r.
// 128n x 256c tile, 512 threads, 66.6 KB LDS -> 2 blocks/CU.
// ---------------------------------------------------------------------------
__global__ __launch_bounds__(512, 4) void transpose_pack_kernel(
    const i32x4* __restrict__ L4, const i32x4* __restrict__ R4,
    unsigned short* __restrict__ LRt, int n0_base, int nslice) {
  __shared__ unsigned short tile[128 * 260];  // 66.6 KB
  const int tn  = blockIdx.x;
  const int gn0 = n0_base + tn * 128;

  // Phase A: 128 rows x 64 quads; per wave 1 KB contiguous loads.
#pragma unroll
  for (int p = 0; p < 16; ++p) {
    const int idx = p * 512 + (int)threadIdx.x;
    const int r   = idx >> 6;   // 0..127
    const int cq  = idx & 63;   // quad within row
    const size_t gi = (size_t)(gn0 + r) * 64 + cq;
    i32x4 Lv = L4[gi];
    i32x4 Rv = R4[gi];
    u16x4 w;
    w[0] = (unsigned short)((Lv[0] << 8) | Rv[0]);
    w[1] = (unsigned short)((Lv[1] << 8) | Rv[1]);
    w[2] = (unsigned short)((Lv[2] << 8) | Rv[2]);
    w[3] = (unsigned short)((Lv[3] << 8) | Rv[3]);
    const int col = (cq * 4) ^ (((r >> 3) & 15) << 2);
    *(u16x4*)&tile[r * 260 + col] = w;
  }
  __syncthreads();

  // Phase B: per pass a wave covers 4 channels x 128 rows (256 B each).
  const int wv = threadIdx.x >> 6;  // 0..7
  const int l  = threadIdx.x & 63;
  const int m  = l & 15;            // 8-row block 0..15
  const int c4 = l >> 4;            // 0..3
#pragma unroll
  for (int p = 0; p < 8; ++p) {
    const int ch = wv * 32 + p * 4 + c4;
    u16x8 v;
#pragma unroll
    for (int j = 0; j < 8; ++j) {
      const int r = m * 8 + j;
      v[j] = tile[r * 260 + (ch ^ (m << 2))];
    }
    *(u16x8*)&LRt[(size_t)ch * nslice + (size_t)tn * 128 + m * 8] = v;
  }
}

// ---------------------------------------------------------------------------
// K2: per-channel code gather, 64 KB table in LDS, 512 threads, 2 blocks/CU.
// Linear [C, nslice] reads (round-4 layout).  Inputs (128 B/thread) loaded
// to VGPR first; table then DMA'd via global_load_lds -- both in flight
// until the single __syncthreads.  blockIdx&255 = channel -> per-XCD L2
// partitions the tables.
// ---------------------------------------------------------------------------
__global__ __launch_bounds__(512, 4) void code_gather_kernel(
    const unsigned short* __restrict__ LRt, const unsigned char* __restrict__ tab8,
    unsigned char* __restrict__ codes, int nslice) {
  __shared__ unsigned char tabs[KK * KK];  // 64 KB
  const int c   = blockIdx.x & (CCH - 1);
  const int sub = blockIdx.x >> 8;
  const int tid = threadIdx.x;
  const size_t base = (size_t)c * nslice + (size_t)sub * 32768;
  const u16x8* __restrict__ in = (const u16x8*)(LRt + base);

  u16x8 v[8];
#pragma unroll
  for (int i = 0; i < 8; ++i) v[i] = in[i * 512 + tid];

  {
    const int w = tid >> 6, lane = tid & 63;
    const unsigned char* tsrc = tab8 + (size_t)c * (KK * KK) + w * 8192 + lane * 16;
    unsigned int* tdst = (unsigned int*)tabs + w * 2048;
#pragma unroll
    for (int i = 0; i < 8; ++i) gl_lds16(tsrc + i * 1024, tdst + i * 256);
  }
  __syncthreads();  // drains vmcnt: table in LDS, inputs in VGPRs

  uint2* outp = (uint2*)(codes + base);
#pragma unroll
  for (int i = 0; i < 8; ++i) {
    unsigned lo = (unsigned)tabs[v[i][0]] | ((unsigned)tabs[v[i][1]] << 8) |
                  ((unsigned)tabs[v[i][2]] << 16) | ((unsigned)tabs[v[i][3]] << 24);
    unsigned hi = (unsigned)tabs[v[i][4]] | ((unsigned)tabs[v[i][5]] << 8) |
                  ((unsigned)tabs[v[i][6]] << 16) | ((unsigned)tabs[v[i][7]] << 24);
    outp[i * 512 + tid] = make_uint2(lo, hi);
  }
}

// ---------------------------------------------------------------------------
// K3: codebook + transpose back (round-5 structure: 3 blocks/CU).
// codes [C,nslice] u8 -> out [N,C] f32.  Tile 256n x 32ch; LDS = 32 KB
// codebook + 8.5 KB pitched code tile.  f32x4 NT stores (128-B segments;
// 8 cg-blocks adjacent in blockIdx fill each 1 KB row on different XCDs).
// ---------------------------------------------------------------------------
__global__ __launch_bounds__(512, 6) void codebook_transpose_kernel(
    const unsigned char* __restrict__ codes, const float* __restrict__ cb,
    float* __restrict__ out, int n0_base, int nslice) {
  __shared__ float    cbs[32 * KK];   // 32 KB
  __shared__ unsigned ctd[32 * 65];   // 8.5 KB, pitch 65 dwords
  const int cg = blockIdx.x & 7;
  const int tn = blockIdx.x >> 3;
  const int c0 = cg * 32;
  const int tid = threadIdx.x;

  {
    const f32x4* cbg = (const f32x4*)(cb + (size_t)c0 * KK);
    f32x4* cbl = (f32x4*)cbs;
#pragma unroll
    for (int i = 0; i < 4; ++i) cbl[i * 512 + tid] = cbg[i * 512 + tid];
  }
  {
    const int cc = tid >> 4;  // 0..31
    const int s  = tid & 15;  // 0..15
    const uint4 val = *(const uint4*)(codes + (size_t)(c0 + cc) * nslice +
                                      (size_t)tn * 256 + s * 16);
    const int d0 = cc * 65 + s * 4;
    ctd[d0 + 0] = val.x;
    ctd[d0 + 1] = val.y;
    ctd[d0 + 2] = val.z;
    ctd[d0 + 3] = val.w;
  }
  __syncthreads();

  const int cq = tid & 7;   // channel quad 0..7
  const int nb = tid >> 3;  // 0..63 (4-row group)
  const unsigned cw0 = ctd[(cq * 4 + 0) * 65 + nb];
  const unsigned cw1 = ctd[(cq * 4 + 1) * 65 + nb];
  const unsigned cw2 = ctd[(cq * 4 + 2) * 65 + nb];
  const unsigned cw3 = ctd[(cq * 4 + 3) * 65 + nb];
  const float* b0 = cbs + (cq * 4 + 0) * KK;
  const float* b1 = cbs + (cq * 4 + 1) * KK;
  const float* b2 = cbs + (cq * 4 + 2) * KK;
  const float* b3 = cbs + (cq * 4 + 3) * KK;
  float* ob = out + (size_t)(n0_base + tn * 256 + nb * 4) * CCH + c0 + cq * 4;
#pragma unroll
  for (int k = 0; k < 4; ++k) {
    f32x4 o;
    o[0] = b0[(cw0 >> (8 * k)) & 255u];
    o[1] = b1[(cw1 >> (8 * k)) & 255u];
    o[2] = b2[(cw2 >> (8 * k)) & 255u];
    o[3] = b3[(cw3 >> (8 * k)) & 255u];
    __builtin_nontemporal_store(o, (f32x4*)(ob + (size_t)k * CCH));
  }
}

// ---------------------------------------------------------------------------
// Fallback: TA-path gather, used only if workspace is tiny.
// ---------------------------------------------------------------------------
#define ROWS_PER_BLOCK 512
#define NGROUPS 16
#define GCH (CCH / NGROUPS)

template <typename TabT>
__global__ __launch_bounds__(256, 8) void gather_kernel(
    const i32x4* __restrict__ left, const i32x4* __restrict__ right,
    const TabT* __restrict__ tab, const float* __restrict__ cb,
    f32x4* __restrict__ out, int nrows) {
  __shared__ float cbs[GCH * KK];
  const int g     = blockIdx.x & (NGROUPS - 1);
  const int chunk = blockIdx.x / NGROUPS;
  const int q     = threadIdx.x & 3;
  const int rsub  = threadIdx.x >> 2;
  {
    const f32x4* cbg = (const f32x4*)(cb + (size_t)(g * GCH) * KK);
    f32x4* cbl = (f32x4*)cbs;
#pragma unroll
    for (int i = 0; i < 4; ++i) cbl[threadIdx.x + i * 256] = cbg[threadIdx.x + i * 256];
  }
  __syncthreads();
  const int cbase  = g * GCH + q * 4;
  const TabT* t0   = tab + (size_t)cbase * (KK * KK);
  const int vecoff = g * 4 + q;
  const float* cq  = cbs + (q * 4) * KK;
  const int rbase = chunk * ROWS_PER_BLOCK;
#pragma unroll
  for (int it = 0; it < ROWS_PER_BLOCK / 32; ++it) {
    const int r0 = rbase + it * 32 + rsub;
    if (r0 >= nrows) break;
    const unsigned v0 = (unsigned)r0 * 64u + (unsigned)vecoff;
    i32x4 L0 = left[v0];
    i32x4 R0 = right[v0];
    unsigned c0 = (unsigned)t0[          (unsigned)(L0[0] * KK + R0[0])];
    unsigned c1 = (unsigned)t0[ 65536u + (unsigned)(L0[1] * KK + R0[1])];
    unsigned c2 = (unsigned)t0[131072u + (unsigned)(L0[2] * KK + R0[2])];
    unsigned c3 = (unsigned)t0[196608u + (unsigned)(L0[3] * KK + R0[3])];
    f32x4 o;
    o[0] = cq[       c0];
    o[1] = cq[KK   + c1];
    o[2] = cq[2*KK + c2];
    o[3] = cq[3*KK + c3];
    out[v0] = o;
  }
}

extern "C" void kernel_launch(void* const* d_in, const int* in_sizes, int n_in,
                              void* d_out, int out_size, void* d_ws, size_t ws_size,
                              hipStream_t stream) {
  const int*   left  = (const int*)d_in[0];
  const int*   right = (const int*)d_in[1];
  const int*   wt    = (const int*)d_in[2];   // [C, K, K] int32
  const float* cb    = (const float*)d_in[3]; // [C, K] float32
  float* out = (float*)d_out;

  const int nrows = in_sizes[0] / CCH;        // 262144
  const int tab_elems = CCH * KK * KK;        // 16,777,216
  const size_t tab_bytes = (size_t)tab_elems; // u8 table = 16 MB

  // Slice the pipeline so per-slice intermediates (768 B/row) stay
  // L2/L3-resident between passes.  Prefer S=4 (49 MB intermediates);
  // larger S if workspace is tighter.  nslice must be a multiple of 32768.
  int S = 0;
  {
    const int prefs[5] = {4, 8, 16, 2, 1};
    for (int pi = 0; pi < 5; ++pi) {
      const int s = prefs[pi];
      if (nrows % (s * 32768)) continue;
      size_t need = tab_bytes + (size_t)768 * (size_t)(nrows / s);
      if (need <= ws_size) { S = s; break; }
    }
  }

  if (S) {
    unsigned char* tab8 = (unsigned char*)d_ws;
    int n4 = tab_elems / 4;
    compress_table_kernel<<<n4 / 256, 256, 0, stream>>>(
        (const int4*)wt, (uchar4*)tab8, n4);

    const int nslice = nrows / S;
    unsigned short* LRt = (unsigned short*)((char*)d_ws + tab_bytes);
    unsigned char* codes = (unsigned char*)d_ws + tab_bytes + (size_t)512 * nslice;

    for (int h = 0; h < S; ++h) {
      const int n0 = h * nslice;
      transpose_pack_kernel<<<nslice / 128, 512, 0, stream>>>(
          (const i32x4*)left, (const i32x4*)right, LRt, n0, nslice);
      code_gather_kernel<<<(nslice / 32768) * CCH, 512, 0, stream>>>(
          LRt, tab8, codes, nslice);
      codebook_transpose_kernel<<<(nslice / 256) * 8, 512, 0, stream>>>(
          codes, cb, out, n0, nslice);
    }
  } else if (ws_size >= tab_bytes) {
    unsigned char* tab8 = (unsigned char*)d_ws;
    int n4 = tab_elems / 4;
    compress_table_kernel<<<n4 / 256, 256, 0, stream>>>(
        (const int4*)wt, (uchar4*)tab8, n4);
    const int blocks = ((nrows + ROWS_PER_BLOCK - 1) / ROWS_PER_BLOCK) * NGROUPS;
    gather_kernel<unsigned char><<<blocks, 256, 0, stream>>>(
        (const i32x4*)left, (const i32x4*)right, tab8, cb, (f32x4*)out, nrows);
  } else {
    const int blocks = ((nrows + ROWS_PER_BLOCK - 1) / ROWS_PER_BLOCK) * NGROUPS;
    gather_kernel<int><<<blocks, 256, 0, stream>>>(
        (const i32x4*)left, (const i32x4*)right, wt, cb, (f32x4*)out, nrows);
  }
}